// Round 11
// baseline (37.755 us; speedup 1.0000x reference)
//
#include <hip/hip_runtime.h>
#include <hip/hip_bf16.h>
#include <math.h>

// LinearAttention: X = Qf @ (Kf^T @ Vm) per (b,h); B=2 H=12 N=4096 D=64 fp32.
// Qf=(elu(Q)+1)*s ; Kf=(elu(K)+1)*m*s ; Vm=V*m ; s = 4096^-0.25 = 0.125.
//
// TWO kernels, exploiting MFMA linearity: X = sum_s (P_s^T @ Qf) where P_s is
// the slab-s partial of KtV.
//  k1: per-block 256-row slab -> KtV^T partial; epilogue transposes via LDS and
//      stores bf16 partial in PASS3 A-FRAGMENT ORDER (16B/thread, coalesced).
//  k2: loads Q B-frags once, then streams slabs: 8x16B A-frag loads + 16 MFMAs
//      per slab, accumulating in fixed slab order (deterministic).

#define BH_TOT 24
#define NROWS 4096
#define DD 64

typedef __attribute__((ext_vector_type(8))) short bf16x8;   // 8 x bf16
typedef __attribute__((ext_vector_type(4))) float f32x4;    // MFMA C/D frag

__device__ __forceinline__ float elu1(float x) {
    return x > 0.0f ? x + 1.0f : __expf(x);
}
__device__ __forceinline__ short f2bf(float x) {
    __hip_bfloat16 h = __float2bfloat16(x);
    return *reinterpret_cast<short*>(&h);
}

// ---------------- Kernel 1: per-block partial KtV^T -> bf16 A-frag order ----------------
// grid (24, slabs), block 256 (4 waves); wave covers chunksPerWave*32 rows.
// Swapped MFMA: acc[je][id] = D[e-tile je][d-tile id]; e=16je+4g+r, d=16id+cl.
__global__ __launch_bounds__(256) void la_pass1(
        const float* __restrict__ K, const float* __restrict__ V,
        const float* __restrict__ mask, bf16x8* __restrict__ partial,
        float scale, int chunksPerWave, int slabs) {
    const int bh   = blockIdx.x;
    const int slab = blockIdx.y;
    const int wave = threadIdx.x >> 6;
    const int lane = threadIdx.x & 63;
    const int g = lane >> 4, rg = g * 8, cl = lane & 15;

    const float* __restrict__ Kp = K + (size_t)bh * NROWS * DD;
    const float* __restrict__ Vp = V + (size_t)bh * NROWS * DD;
    const float* __restrict__ mp = mask + (size_t)(bh / 12) * NROWS;

    f32x4 acc[4][4];   // [je][id]
#pragma unroll
    for (int je = 0; je < 4; ++je)
#pragma unroll
        for (int id = 0; id < 4; ++id) acc[je][id] = (f32x4)0.0f;

    const int n0 = (slab * 4 + wave) * chunksPerWave * 32;

#pragma unroll 1
    for (int c = 0; c < chunksPerWave; ++c) {
        const int nb = n0 + c * 32 + rg;              // this lane's 8-row group
        const float* kb = Kp + (size_t)nb * DD + cl;
        const float* vb = Vp + (size_t)nb * DD + cl;
        float mrow[8], kr[8][4], vr[8][4];
#pragma unroll
        for (int jj = 0; jj < 8; ++jj) {
            mrow[jj] = mp[nb + jj];
#pragma unroll
            for (int i = 0; i < 4; ++i) {
                kr[jj][i] = kb[jj * DD + i * 16];     // imm-offset dword loads
                vr[jj][i] = vb[jj * DD + i * 16];
            }
        }
        bf16x8 af[4], bv[4];
#pragma unroll
        for (int i = 0; i < 4; ++i)
#pragma unroll
            for (int jj = 0; jj < 8; ++jj) {
                af[i][jj] = f2bf(elu1(kr[jj][i]) * (mrow[jj] * scale));
                bv[i][jj] = f2bf(vr[jj][i] * mrow[jj]);
            }
        // D[e][d] = sum_n Vm[n][e] * Kf[n][d]
#pragma unroll
        for (int je = 0; je < 4; ++je)
#pragma unroll
            for (int id = 0; id < 4; ++id)
                acc[je][id] = __builtin_amdgcn_mfma_f32_16x16x32_bf16(
                                  bv[je], af[id], acc[je][id], 0, 0, 0);
    }

    // ---- cross-wave reduce, fragment-native (b128, conflict-free) ----
    __shared__ f32x4 red[2][16][64];      // 32 KB
    __shared__ float T[64][67];           // transpose buffer, pad 67
    if (wave >= 2) {
#pragma unroll
        for (int je = 0; je < 4; ++je)
#pragma unroll
            for (int id = 0; id < 4; ++id)
                red[wave - 2][je * 4 + id][lane] = acc[je][id];
    }
    __syncthreads();
    if (wave < 2) {
#pragma unroll
        for (int je = 0; je < 4; ++je)
#pragma unroll
            for (int id = 0; id < 4; ++id)
                acc[je][id] += red[wave][je * 4 + id][lane];
    }
    __syncthreads();
    if (wave == 1) {
#pragma unroll
        for (int je = 0; je < 4; ++je)
#pragma unroll
            for (int id = 0; id < 4; ++id)
                red[0][je * 4 + id][lane] = acc[je][id];
    }
    __syncthreads();
    if (wave == 0) {
        // final sum -> T[e][d]  (banks ~2-way: (8g+2r+16id+cl) spread)
#pragma unroll
        for (int je = 0; je < 4; ++je)
#pragma unroll
            for (int id = 0; id < 4; ++id) {
            f32x4 v = acc[je][id] + red[0][je * 4 + id][lane];
#pragma unroll
            for (int r = 0; r < 4; ++r)
                T[16 * je + 4 * g + r][16 * id + cl] = v[r];
        }
    }
    __syncthreads();

    // ---- all 256 threads: pack bf16 A-frags and store coalesced ----
    // fw = (i*2+c2)*64 + ln ; A[row=16i+cl2][k=32c2+8g2+jj] = T[16i+cl2][32c2+8g2+jj]
    bf16x8* out = partial + ((size_t)bh * slabs + slab) * 512;
#pragma unroll
    for (int k = 0; k < 2; ++k) {
        const int fw = threadIdx.x + k * 256;          // 0..511
        const int i  = fw >> 7;
        const int c2 = (fw >> 6) & 1;
        const int ln = fw & 63;
        const int g2 = ln >> 4, cl2 = ln & 15;
        bf16x8 w;
#pragma unroll
        for (int jj = 0; jj < 8; ++jj)
            w[jj] = f2bf(T[16 * i + cl2][32 * c2 + 8 * g2 + jj]);
        out[fw] = w;
    }
}

// ---------------- Kernel 2: X = sum_s P_s^T @ Qf (swapped operands) ----------------
// grid (24, 32), block 256; wave handles 32 rows (t=0..1 n-tiles).
__global__ __launch_bounds__(256) void la_pass3(
        const float* __restrict__ Q, const bf16x8* __restrict__ partial,
        float* __restrict__ X, float scale, int slabs) {
    const int bh   = blockIdx.x;
    const int wave = threadIdx.x >> 6;
    const int lane = threadIdx.x & 63;
    const int n0   = blockIdx.y * 128 + wave * 32;
    const int g = lane >> 4, rg = g * 8, cl = lane & 15;

    // B-frag(t,c2): B[k=32c2+rg+jj][col=16t+cl] = Qf[n0+16t+cl][32c2+rg+jj]
    const float* Qp = Q + (size_t)bh * NROWS * DD;
    bf16x8 bfr[2][2];
#pragma unroll
    for (int t = 0; t < 2; ++t)
#pragma unroll
        for (int c2 = 0; c2 < 2; ++c2) {
            const float* qp = Qp + (size_t)(n0 + 16 * t + cl) * DD + 32 * c2 + rg;
            float4 q0 = ((const float4*)qp)[0];
            float4 q1 = ((const float4*)qp)[1];
            bf16x8 a;
            a[0] = f2bf(elu1(q0.x) * scale); a[1] = f2bf(elu1(q0.y) * scale);
            a[2] = f2bf(elu1(q0.z) * scale); a[3] = f2bf(elu1(q0.w) * scale);
            a[4] = f2bf(elu1(q1.x) * scale); a[5] = f2bf(elu1(q1.y) * scale);
            a[6] = f2bf(elu1(q1.z) * scale); a[7] = f2bf(elu1(q1.w) * scale);
            bfr[t][c2] = a;
        }

    f32x4 acc[4][2];
#pragma unroll
    for (int i = 0; i < 4; ++i)
#pragma unroll
        for (int t = 0; t < 2; ++t) acc[i][t] = (f32x4)0.0f;

    // stream slabs in FIXED order (deterministic); partials are L2/L3-hot
    const bf16x8* pb = partial + (size_t)bh * slabs * 512;
#pragma unroll 2
    for (int s = 0; s < slabs; ++s) {
        const bf16x8* ps = pb + (size_t)s * 512;
        bf16x8 afr[4][2];
#pragma unroll
        for (int i = 0; i < 4; ++i)
#pragma unroll
            for (int c2 = 0; c2 < 2; ++c2)
                afr[i][c2] = ps[(i * 2 + c2) * 64 + lane];   // 16B, coalesced
#pragma unroll
        for (int i = 0; i < 4; ++i)
#pragma unroll
            for (int t = 0; t < 2; ++t) {
                acc[i][t] = __builtin_amdgcn_mfma_f32_16x16x32_bf16(
                                afr[i][0], bfr[t][0], acc[i][t], 0, 0, 0);
                acc[i][t] = __builtin_amdgcn_mfma_f32_16x16x32_bf16(
                                afr[i][1], bfr[t][1], acc[i][t], 0, 0, 0);
            }
    }

    // store: X[n0+16t+cl][16i+4g .. +3] <- acc[i][t][0..3]  (float4)
    float* Xp = X + (size_t)bh * NROWS * DD;
#pragma unroll
    for (int i = 0; i < 4; ++i)
#pragma unroll
        for (int t = 0; t < 2; ++t) {
            float4 v = make_float4(acc[i][t][0], acc[i][t][1],
                                   acc[i][t][2], acc[i][t][3]);
            *reinterpret_cast<float4*>(
                Xp + (size_t)(n0 + 16 * t + cl) * DD + 16 * i + 4 * g) = v;
        }
}

extern "C" void kernel_launch(void* const* d_in, const int* in_sizes, int n_in,
                              void* d_out, int out_size, void* d_ws, size_t ws_size,
                              hipStream_t stream) {
    const float* Q    = (const float*)d_in[0];
    const float* K    = (const float*)d_in[1];
    const float* V    = (const float*)d_in[2];
    const float* mask = (const float*)d_in[3];
    float* X = (float*)d_out;

    const float scale = 0.125f;   // 4096^-0.25 exactly

    // slabs per head (256 rows each by default); bf16 partial = 8 KB/slab
    int slabs = 16;
    while (slabs > 4 && (size_t)BH_TOT * slabs * 8192 > ws_size)
        slabs >>= 1;
    const int chunksPerWave = NROWS / (slabs * 128);   // = 2 at slabs=16

    bf16x8* partial = (bf16x8*)d_ws;

    la_pass1<<<dim3(BH_TOT, slabs), 256, 0, stream>>>(K, V, mask, partial,
                                                      scale, chunksPerWave, slabs);
    la_pass3<<<dim3(BH_TOT, 32), 256, 0, stream>>>(Q, partial, X, scale, slabs);
}

// Round 12
// 33.776 us; speedup vs baseline: 1.1178x; 1.1178x over previous
//
#include <hip/hip_runtime.h>
#include <hip/hip_bf16.h>
#include <math.h>

// LinearAttention: X = Qf @ (Kf^T @ Vm) per (b,h); B=2 H=12 N=4096 D=64 fp32.
// Qf=(elu(Q)+1)*s ; Kf=(elu(K)+1)*m*s ; Vm=V*m ; s = 4096^-0.25 = 0.125.
//
// 3 kernels (R10 structure), retuned for LATENCY DEPTH (>=3 waves/SIMD):
//  pass1: grid (24,32) x 256thr, ONE 32-row chunk per wave -> 3 blocks/CU,
//         3 waves/SIMD. Partial stored fragment-native fp32 (12.6 MB).
//  pass2: elementwise 32-slab reduce -> bf16 ktvT[e][d].
//  pass3: grid (24,64) x 256thr, 16 rows/wave -> ~6 blocks/CU.

#define BH_TOT 24
#define NROWS 4096
#define DD 64
#define SLABS 32

typedef __attribute__((ext_vector_type(8))) short bf16x8;   // 8 x bf16
typedef __attribute__((ext_vector_type(4))) float f32x4;    // MFMA C/D frag

__device__ __forceinline__ float elu1(float x) {
    return x > 0.0f ? x + 1.0f : __expf(x);
}
__device__ __forceinline__ short f2bf(float x) {
    __hip_bfloat16 h = __float2bfloat16(x);
    return *reinterpret_cast<short*>(&h);
}

// ---------------- Pass 1: per-block partial KtV^T (fragment-native) ----------------
// grid (24, 32), block 256 (4 waves); each wave ONE 32-row chunk.
// Swapped MFMA: acc[je][id] = D[e-tile je][d-tile id]; e=16je+4g+r, d=16id+cl.
__global__ __launch_bounds__(256) void la_pass1(
        const float* __restrict__ K, const float* __restrict__ V,
        const float* __restrict__ mask, float* __restrict__ partial,
        float scale) {
    const int bh   = blockIdx.x;
    const int slab = blockIdx.y;
    const int wave = threadIdx.x >> 6;
    const int lane = threadIdx.x & 63;
    const int g = lane >> 4, rg = g * 8, cl = lane & 15;

    const float* __restrict__ Kp = K + (size_t)bh * NROWS * DD;
    const float* __restrict__ Vp = V + (size_t)bh * NROWS * DD;
    const float* __restrict__ mp = mask + (size_t)(bh / 12) * NROWS;

    f32x4 acc[4][4];   // [je][id]
#pragma unroll
    for (int je = 0; je < 4; ++je)
#pragma unroll
        for (int id = 0; id < 4; ++id) acc[je][id] = (f32x4)0.0f;

    const int nb = (slab * 4 + wave) * 32 + rg;       // this lane's 8-row group
    {
        const float* kb = Kp + (size_t)nb * DD + cl;
        const float* vb = Vp + (size_t)nb * DD + cl;
        float mrow[8], kr[8][4], vr[8][4];
#pragma unroll
        for (int jj = 0; jj < 8; ++jj) {
            mrow[jj] = mp[nb + jj];
#pragma unroll
            for (int i = 0; i < 4; ++i) {
                kr[jj][i] = kb[jj * DD + i * 16];     // imm-offset dword loads
                vr[jj][i] = vb[jj * DD + i * 16];
            }
        }
        bf16x8 af[4], bv[4];
#pragma unroll
        for (int i = 0; i < 4; ++i)
#pragma unroll
            for (int jj = 0; jj < 8; ++jj) {
                af[i][jj] = f2bf(elu1(kr[jj][i]) * (mrow[jj] * scale));
                bv[i][jj] = f2bf(vr[jj][i] * mrow[jj]);
            }
        // D[e][d] = sum_n Vm[n][e] * Kf[n][d]
#pragma unroll
        for (int je = 0; je < 4; ++je)
#pragma unroll
            for (int id = 0; id < 4; ++id)
                acc[je][id] = __builtin_amdgcn_mfma_f32_16x16x32_bf16(
                                  bv[je], af[id], acc[je][id], 0, 0, 0);
    }

    // ---- cross-wave reduce, fragment-native (all b128, conflict-free) ----
    __shared__ f32x4 red[2][16][64];      // 32 KB
    if (wave >= 2) {
#pragma unroll
        for (int je = 0; je < 4; ++je)
#pragma unroll
            for (int id = 0; id < 4; ++id)
                red[wave - 2][je * 4 + id][lane] = acc[je][id];
    }
    __syncthreads();
    if (wave < 2) {
#pragma unroll
        for (int je = 0; je < 4; ++je)
#pragma unroll
            for (int id = 0; id < 4; ++id)
                acc[je][id] += red[wave][je * 4 + id][lane];
    }
    __syncthreads();
    if (wave == 1) {
#pragma unroll
        for (int je = 0; je < 4; ++je)
#pragma unroll
            for (int id = 0; id < 4; ++id)
                red[0][je * 4 + id][lane] = acc[je][id];
    }
    __syncthreads();
    if (wave == 0) {
        f32x4* out = (f32x4*)partial + ((size_t)bh * SLABS + slab) * 1024;
#pragma unroll
        for (int je = 0; je < 4; ++je)
#pragma unroll
            for (int id = 0; id < 4; ++id)
                out[(je * 4 + id) * 64 + lane]
                    = acc[je][id] + red[0][je * 4 + id][lane];
    }
}

// ---------------- Pass 2: reduce slabs -> bf16 ktvT[e][d] ----------------
// grid (24, 4), block 256. One f32x4 position per thread: pos in [0,1024).
// pos = frag*64 + ln ; frag = je*4+id ; e0 = 16*je + 4*(ln>>4) ; d = 16*id + (ln&15).
__global__ __launch_bounds__(256) void la_pass2(
        const float* __restrict__ partial, __hip_bfloat16* __restrict__ ktvT) {
    const int bh  = blockIdx.x;
    const int pos = blockIdx.y * 256 + threadIdx.x;    // 0..1023 (f32x4 idx)
    const f32x4* base = (const f32x4*)partial + (size_t)bh * SLABS * 1024 + pos;
    f32x4 s = (f32x4)0.0f;
#pragma unroll 8
    for (int w = 0; w < SLABS; ++w)
        s += base[(size_t)w * 1024];
    const int frag = pos >> 6, ln = pos & 63;
    const int e0 = 16 * (frag >> 2) + 4 * (ln >> 4);
    const int d  = 16 * (frag & 3) + (ln & 15);
    __hip_bfloat16* ko = ktvT + (size_t)bh * DD * DD;
#pragma unroll
    for (int r = 0; r < 4; ++r)
        ko[(size_t)(e0 + r) * DD + d] = __float2bfloat16(s[r]);
}

// ---------------- Pass 3: X = Qf @ KtV (swapped operands), 16 rows/wave ----------------
// grid (24, 64), block 256 (4 waves); wave handles ONE 16-row n-tile.
__global__ __launch_bounds__(256) void la_pass3(
        const float* __restrict__ Q, const __hip_bfloat16* __restrict__ ktvT,
        float* __restrict__ X, float scale) {
    const int bh   = blockIdx.x;
    const int wave = threadIdx.x >> 6;
    const int lane = threadIdx.x & 63;
    const int n0   = blockIdx.y * 64 + wave * 16;
    const int g = lane >> 4, rg = g * 8, cl = lane & 15;

    // B-frag(c2): B[k=32c2+rg+jj][col=cl] = Qf[n0+cl][32c2+rg+jj]  (2x float4)
    const float* Qp = Q + (size_t)bh * NROWS * DD;
    bf16x8 bfr[2];
#pragma unroll
    for (int c2 = 0; c2 < 2; ++c2) {
        const float* qp = Qp + (size_t)(n0 + cl) * DD + 32 * c2 + rg;
        float4 q0 = ((const float4*)qp)[0];
        float4 q1 = ((const float4*)qp)[1];
        bf16x8 a;
        a[0] = f2bf(elu1(q0.x) * scale); a[1] = f2bf(elu1(q0.y) * scale);
        a[2] = f2bf(elu1(q0.z) * scale); a[3] = f2bf(elu1(q0.w) * scale);
        a[4] = f2bf(elu1(q1.x) * scale); a[5] = f2bf(elu1(q1.y) * scale);
        a[6] = f2bf(elu1(q1.z) * scale); a[7] = f2bf(elu1(q1.w) * scale);
        bfr[c2] = a;
    }

    // A-frag(i,c2): A[row=16i+cl][k=32c2+rg+jj] = ktvT[16i+cl][32c2+rg+jj] (16B)
    bf16x8 afr[4][2];
#pragma unroll
    for (int i = 0; i < 4; ++i)
#pragma unroll
        for (int c2 = 0; c2 < 2; ++c2)
            afr[i][c2] = *reinterpret_cast<const bf16x8*>(
                ktvT + (size_t)bh * DD * DD + (size_t)(16 * i + cl) * DD + 32 * c2 + rg);

    f32x4 acc[4];
#pragma unroll
    for (int i = 0; i < 4; ++i) acc[i] = (f32x4)0.0f;

#pragma unroll
    for (int i = 0; i < 4; ++i) {
        acc[i] = __builtin_amdgcn_mfma_f32_16x16x32_bf16(
                     afr[i][0], bfr[0], acc[i], 0, 0, 0);
        acc[i] = __builtin_amdgcn_mfma_f32_16x16x32_bf16(
                     afr[i][1], bfr[1], acc[i], 0, 0, 0);
    }

    // store: X[n0+cl][16i+4g .. +3] <- acc[i][0..3]  (float4)
    float* Xp = X + (size_t)bh * NROWS * DD;
#pragma unroll
    for (int i = 0; i < 4; ++i) {
        float4 v = make_float4(acc[i][0], acc[i][1], acc[i][2], acc[i][3]);
        *reinterpret_cast<float4*>(
            Xp + (size_t)(n0 + cl) * DD + 16 * i + 4 * g) = v;
    }
}

extern "C" void kernel_launch(void* const* d_in, const int* in_sizes, int n_in,
                              void* d_out, int out_size, void* d_ws, size_t ws_size,
                              hipStream_t stream) {
    const float* Q    = (const float*)d_in[0];
    const float* K    = (const float*)d_in[1];
    const float* V    = (const float*)d_in[2];
    const float* mask = (const float*)d_in[3];
    float* X = (float*)d_out;

    const float scale = 0.125f;   // 4096^-0.25 exactly

    float* partial = (float*)d_ws;                        // 24*32*16KB = 12.6 MB
    __hip_bfloat16* ktvT =
        (__hip_bfloat16*)((char*)d_ws + (size_t)BH_TOT * SLABS * DD * DD * 4);

    la_pass1<<<dim3(BH_TOT, SLABS), 256, 0, stream>>>(K, V, mask, partial, scale);
    la_pass2<<<dim3(BH_TOT, 4), 256, 0, stream>>>(partial, ktvT);
    la_pass3<<<dim3(BH_TOT, 64), 256, 0, stream>>>(Q, ktvT, X, scale);
}